// Round 5
// baseline (303.451 us; speedup 1.0000x reference)
//
#include <hip/hip_runtime.h>
#include <hip/hip_bf16.h>
#include <math.h>

// Problem constants
#define Bn 8
#define Sn 4096
#define Dn 512
#define MODES 16
#define ANGF 0.0015339807878856412f  // 2*pi/4096
#define NCHUNK 32
#define CH (Sn / NCHUNK)  // 128 rows per chunk

// ws layout (floats):
//   partials : 0         4,194,304   fp32 [B*32][16][512][2]
//   Y        : 4,194,304   131,072   fp32 [B][16][512][2]
//   wTf      : 4,325,376   786,432   fp32 [3][512 d][512 o]
//   Z        : 5,111,808   393,216   fp32 [B][3][16][512][2]
//   G        : 5,505,024   131,072   fp32 [B][16][2][512]
//   V        : 5,636,096     8,192   fp32 [B][2][512]
#define PART_OFF 0
#define Y_OFF 4194304
#define WTF_OFF 4325376
#define Z_OFF 5111808
#define G_OFF 5505024
#define V_OFF 5636096

// ---------------------------------------------------------------------------
// K0: transpose conv_w (O,I,3) -> wTf[t][d][o] fp32 (coalesced o-loads later)
// ---------------------------------------------------------------------------
__global__ __launch_bounds__(256) void k_transpose_w(
    const float* __restrict__ cw, float* __restrict__ wTf) {
  int idx = blockIdx.x * 256 + threadIdx.x;  // 786432
  int o = idx & 511;
  int d = (idx >> 9) & 511;
  int t = idx >> 18;
  wTf[idx] = cw[o * 1536 + d * 3 + t];
}

// ---------------------------------------------------------------------------
// K1: fused LayerNorm + 16-mode DFT projection, per-128-row-chunk partials.
// Phase 1: per-row mean/rstd (wave w handles rows w*32..+31).
// Phase 2: barrier-free accumulation with precomputed twiddle table.
// ---------------------------------------------------------------------------
__global__ __launch_bounds__(256) void k_ln_project(
    const float* __restrict__ x, const float* __restrict__ gamma,
    const float* __restrict__ beta, float* __restrict__ partials) {
  int b = blockIdx.x / NCHUNK;
  int c = blockIdx.x % NCHUNK;
  int tid = threadIdx.x;
  int lane = tid & 63, wave = tid >> 6;
  int s_base = c * CH;

  __shared__ float2 s_tw[CH * MODES];  // [row][mode] = (cos, sin) 16 KB
  __shared__ float2 s_mv[CH];          // (mu, rstd)

#pragma unroll
  for (int u = 0; u < 8; u++) {
    int idx = tid * 8 + u;  // 2048
    int r = idx >> 4, k = idx & 15;
    int m = ((s_base + r) * k) & (Sn - 1);
    float sn, cn;
    sincosf((float)m * ANGF, &sn, &cn);
    s_tw[idx] = make_float2(cn, sn);
  }

  for (int j = 0; j < 32; j++) {
    int r = wave * 32 + j;
    const float4* px = (const float4*)&x[((size_t)(b * Sn + s_base + r)) << 9];
    float4 v0 = px[lane * 2];
    float4 v1 = px[lane * 2 + 1];
    float ps = v0.x + v0.y + v0.z + v0.w + v1.x + v1.y + v1.z + v1.w;
    float pq = v0.x * v0.x + v0.y * v0.y + v0.z * v0.z + v0.w * v0.w +
               v1.x * v1.x + v1.y * v1.y + v1.z * v1.z + v1.w * v1.w;
#pragma unroll
    for (int off = 32; off > 0; off >>= 1) {
      ps += __shfl_down(ps, off);
      pq += __shfl_down(pq, off);
    }
    if (lane == 0) {
      float mu = ps * (1.0f / Dn);
      float var = pq * (1.0f / Dn) - mu * mu;
      s_mv[r] = make_float2(mu, rsqrtf(var + 1e-5f));
    }
  }
  __syncthreads();

  int d0 = tid * 2;
  float g0 = gamma[d0], g1 = gamma[d0 + 1];
  float be0 = beta[d0], be1 = beta[d0 + 1];
  float accRe0[MODES], accRe1[MODES], accIm0[MODES], accIm1[MODES];
#pragma unroll
  for (int k = 0; k < MODES; k++) {
    accRe0[k] = 0.f; accRe1[k] = 0.f; accIm0[k] = 0.f; accIm1[k] = 0.f;
  }
  for (int r = 0; r < CH; ++r) {
    float2 xv = *(const float2*)&x[(((size_t)(b * Sn + s_base + r)) << 9) + d0];
    float2 mv = s_mv[r];
    float xn0 = (xv.x - mv.x) * mv.y * g0 + be0;
    float xn1 = (xv.y - mv.x) * mv.y * g1 + be1;
    const float2* tw = &s_tw[r * MODES];
#pragma unroll
    for (int k = 0; k < MODES; k++) {
      float2 cs = tw[k];
      accRe0[k] += xn0 * cs.x;
      accRe1[k] += xn1 * cs.x;
      accIm0[k] -= xn0 * cs.y;
      accIm1[k] -= xn1 * cs.y;
    }
  }
  size_t base = ((size_t)(b * NCHUNK + c)) * MODES;
#pragma unroll
  for (int k = 0; k < MODES; k++) {
    float4 v = make_float4(accRe0[k], accIm0[k], accRe1[k], accIm1[k]);
    *(float4*)&partials[(((base + k) * Dn) + (size_t)d0) * 2] = v;
  }
}

// ---------------------------------------------------------------------------
// K2: reduce partials over chunks, apply spectral weight, fold ortho norms
// (1/4096; 2/4096 for k>=1 Hermitian fold). Convention (verified R2-R4):
// xs[s,d] = sum_k (Yre cos - Yim sin) = Re(E_k(s) * Yhat[k,d]).
// ---------------------------------------------------------------------------
__global__ __launch_bounds__(256) void k_reduce_modes(
    const float* __restrict__ partials, const float* __restrict__ wr,
    const float* __restrict__ wi, float* __restrict__ Y) {
  int idx = blockIdx.x * 256 + threadIdx.x;  // 65536
  int d = idx & 511;
  int k = (idx >> 9) & 15;
  int b = idx >> 13;
  const float2* P = (const float2*)partials;
  float re = 0.f, im = 0.f;
#pragma unroll 8
  for (int c = 0; c < NCHUNK; c++) {
    float2 p = P[(((size_t)(b * NCHUNK + c)) * MODES + k) * Dn + d];
    re += p.x;
    im += p.y;
  }
  float wrv = wr[d * MODES + k];
  float wiv = wi[d * MODES + k];
  float yre = re * wrv - im * wiv;
  float yim = re * wiv + im * wrv;
  float scale = (k == 0) ? (1.0f / 4096.0f) : (2.0f / 4096.0f);
  ((float2*)Y)[((size_t)b * MODES + k) * Dn + d] =
      make_float2(yre * scale, yim * scale);
}

// ---------------------------------------------------------------------------
// KZ: Z[b][t][k][o] = sum_d Yhat[b,k,d] * w[o,d,t]  (complex * real).
// Grid 192 = b(8) x t(3) x och(8 of 64 o). Wave = 4 modes (kq), lanes = o.
// Y chunk staged in LDS ([16][64] float2, broadcast reads).
// ---------------------------------------------------------------------------
__global__ __launch_bounds__(256) void k_build_z(
    const float* __restrict__ Y, const float* __restrict__ wTf,
    float* __restrict__ Z) {
  int blk = blockIdx.x;
  int b = blk / 24;
  int rem = blk % 24;
  int t = rem >> 3;
  int och = rem & 7;
  int tid = threadIdx.x;
  int oi = tid & 63, kq = tid >> 6;
  int o = och * 64 + oi;

  __shared__ float2 Ys[16][64];  // 8 KB
  const float2* Y2 = (const float2*)Y;

  float zc[4] = {0.f, 0.f, 0.f, 0.f}, zs[4] = {0.f, 0.f, 0.f, 0.f};
  for (int cch = 0; cch < 8; ++cch) {
    int dd0 = cch * 64;
    __syncthreads();
#pragma unroll
    for (int i = 0; i < 4; i++) {
      int e = tid + i * 256;  // 1024 entries
      int k = e >> 6, dd = e & 63;
      Ys[k][dd] = Y2[(((size_t)(b * MODES + k)) << 9) + dd0 + dd];
    }
    __syncthreads();
#pragma unroll 8
    for (int dd = 0; dd < 64; ++dd) {
      float wv = wTf[((size_t)(t * Dn + dd0 + dd) << 9) + o];
#pragma unroll
      for (int m = 0; m < 4; m++) {
        float2 y = Ys[kq * 4 + m][dd];
        zc[m] += y.x * wv;
        zs[m] += y.y * wv;
      }
    }
  }
  float2* Z2 = (float2*)Z;
#pragma unroll
  for (int m = 0; m < 4; m++) {
    int k = kq * 4 + m;
    Z2[(((size_t)((b * 3 + t) * MODES + k)) << 9) + o] =
        make_float2(zc[m], zs[m]);
  }
}

// ---------------------------------------------------------------------------
// KG: G[b][k][o] = Yhat + e^{-i phi} Z0 + Z1 + e^{+i phi} Z2  (phi = 2pi k/S)
// plus boundary vectors V0[b,o] = sum_k Re(e^{-i phi_k} Z0[k,o]) (row s=0
// wrap correction) and V1[b,o] = sum_k Re(Z2[k,o]) (row s=S-1).
// ---------------------------------------------------------------------------
__global__ __launch_bounds__(256) void k_build_g(
    const float* __restrict__ Y, const float* __restrict__ Z,
    float* __restrict__ G, float* __restrict__ V) {
  int idx = blockIdx.x * 256 + threadIdx.x;
  const float2* Y2 = (const float2*)Y;
  const float2* Z2 = (const float2*)Z;
  if (idx < 65536) {
    int o = idx & 511;
    int k = (idx >> 9) & 15;
    int b = idx >> 13;
    float2 y = Y2[(((size_t)(b * MODES + k)) << 9) + o];
    float2 z0 = Z2[(((size_t)((b * 3 + 0) * MODES + k)) << 9) + o];
    float2 z1 = Z2[(((size_t)((b * 3 + 1) * MODES + k)) << 9) + o];
    float2 z2 = Z2[(((size_t)((b * 3 + 2) * MODES + k)) << 9) + o];
    float sf, cf;
    sincosf((float)k * ANGF, &sf, &cf);
    float gc = y.x + (cf * z0.x + sf * z0.y) + z1.x + (cf * z2.x - sf * z2.y);
    float gs = y.y + (cf * z0.y - sf * z0.x) + z1.y + (cf * z2.y + sf * z2.x);
    G[(((size_t)(b * MODES + k) * 2 + 0)) << 9 | o] = gc;
    G[(((size_t)(b * MODES + k) * 2 + 1)) << 9 | o] = gs;
  } else if (idx < 65536 + 8192) {
    int j = idx - 65536;
    int o = j & 511;
    int comp = (j >> 9) & 1;
    int b = j >> 10;
    float v = 0.f;
    if (comp == 0) {
#pragma unroll
      for (int k = 0; k < MODES; k++) {
        float2 z0 = Z2[(((size_t)((b * 3 + 0) * MODES + k)) << 9) + o];
        float sf, cf;
        sincosf((float)k * ANGF, &sf, &cf);
        v += cf * z0.x + sf * z0.y;
      }
    } else {
#pragma unroll
      for (int k = 0; k < MODES; k++) {
        float2 z2 = Z2[(((size_t)((b * 3 + 2) * MODES + k)) << 9) + o];
        v += z2.x;
      }
    }
    V[((size_t)(b * 2 + comp) << 9) + o] = v;
  }
}

// ---------------------------------------------------------------------------
// K5: out[b,s,o] = x + conv_b[o] + sum_k (cos th_ks * Gc[k,o] - sin * Gs[k,o])
// minus V0 on s=0 and V1 on s=4095 (zero-pad vs circular correction).
// Grid 512 = b(8) x stile(64 of 64 rows). Thread: o0 = (tid&127)*4,
// rows rh*32..+31. G fragments held in registers (32 float4).
// ---------------------------------------------------------------------------
__global__ __launch_bounds__(256) void k_apply(
    const float* __restrict__ x, const float* __restrict__ G,
    const float* __restrict__ V, const float* __restrict__ conv_b,
    float* __restrict__ out) {
  int b = blockIdx.x >> 6;
  int st = blockIdx.x & 63;
  int s0 = st * 64;
  int tid = threadIdx.x;
  int oi = tid & 127, rh = tid >> 7;
  int o0 = oi * 4;

  __shared__ float2 s_tw[64][MODES];  // 8 KB
#pragma unroll
  for (int u = 0; u < 4; u++) {
    int e = tid * 4 + u;  // 1024
    int r = e >> 4, k = e & 15;
    int m = ((s0 + r) * k) & (Sn - 1);
    float sn, cn;
    sincosf((float)m * ANGF, &sn, &cn);
    s_tw[r][k] = make_float2(cn, sn);
  }

  float4 Gc4[MODES], Gs4[MODES];
  const float4* Gp = (const float4*)(G + ((size_t)b * MODES * 2 * Dn));
#pragma unroll
  for (int k = 0; k < MODES; k++) {
    Gc4[k] = Gp[(k * 2 + 0) * 128 + oi];
    Gs4[k] = Gp[(k * 2 + 1) * 128 + oi];
  }
  float4 cb4 = *(const float4*)&conv_b[o0];
  __syncthreads();

  for (int rr = 0; rr < 32; ++rr) {
    int r = rh * 32 + rr;
    int s = s0 + r;
    float4 x4 = *(const float4*)&x[(((size_t)(b * Sn + s)) << 9) + o0];
    float ax = 0.f, ay = 0.f, az = 0.f, aw = 0.f;
    const float2* twr = &s_tw[r][0];
#pragma unroll
    for (int k = 0; k < MODES; k++) {
      float2 cs = twr[k];  // LDS broadcast
      ax += cs.x * Gc4[k].x - cs.y * Gs4[k].x;
      ay += cs.x * Gc4[k].y - cs.y * Gs4[k].y;
      az += cs.x * Gc4[k].z - cs.y * Gs4[k].z;
      aw += cs.x * Gc4[k].w - cs.y * Gs4[k].w;
    }
    if (s == 0) {
      float4 v = *(const float4*)&V[((size_t)(b * 2 + 0) << 9) + o0];
      ax -= v.x; ay -= v.y; az -= v.z; aw -= v.w;
    }
    if (s == Sn - 1) {
      float4 v = *(const float4*)&V[((size_t)(b * 2 + 1) << 9) + o0];
      ax -= v.x; ay -= v.y; az -= v.z; aw -= v.w;
    }
    float4 o4;
    o4.x = x4.x + cb4.x + ax;
    o4.y = x4.y + cb4.y + ay;
    o4.z = x4.z + cb4.z + az;
    o4.w = x4.w + cb4.w + aw;
    *(float4*)&out[(((size_t)(b * Sn + s)) << 9) + o0] = o4;
  }
}

// ---------------------------------------------------------------------------
extern "C" void kernel_launch(void* const* d_in, const int* in_sizes, int n_in,
                              void* d_out, int out_size, void* d_ws,
                              size_t ws_size, hipStream_t stream) {
  const float* x = (const float*)d_in[0];
  const float* gamma = (const float*)d_in[1];
  const float* beta = (const float*)d_in[2];
  const float* wr = (const float*)d_in[3];
  const float* wi = (const float*)d_in[4];
  const float* conv_w = (const float*)d_in[5];
  const float* conv_b = (const float*)d_in[6];
  float* out = (float*)d_out;

  float* ws = (float*)d_ws;
  float* partials = ws + PART_OFF;
  float* Y = ws + Y_OFF;
  float* wTf = ws + WTF_OFF;
  float* Z = ws + Z_OFF;
  float* G = ws + G_OFF;
  float* V = ws + V_OFF;

  hipLaunchKernelGGL(k_transpose_w, dim3(3072), dim3(256), 0, stream, conv_w,
                     wTf);
  hipLaunchKernelGGL(k_ln_project, dim3(Bn * NCHUNK), dim3(256), 0, stream, x,
                     gamma, beta, partials);
  hipLaunchKernelGGL(k_reduce_modes, dim3(256), dim3(256), 0, stream, partials,
                     wr, wi, Y);
  hipLaunchKernelGGL(k_build_z, dim3(192), dim3(256), 0, stream, Y, wTf, Z);
  hipLaunchKernelGGL(k_build_g, dim3(288), dim3(256), 0, stream, Y, Z, G, V);
  hipLaunchKernelGGL(k_apply, dim3(512), dim3(256), 0, stream, x, G, V, conv_b,
                     out);
}

// Round 6
// 212.762 us; speedup vs baseline: 1.4262x; 1.4262x over previous
//
#include <hip/hip_runtime.h>
#include <hip/hip_bf16.h>
#include <math.h>

// Problem constants
#define Bn 8
#define Sn 4096
#define Dn 512
#define MODES 16
#define ANGF 0.0015339807878856412f  // 2*pi/4096

// ws layout (floats):
#define PART_OFF 0               //  8,388,608  fp32 [B*64][16][512] float2
#define Y_OFF 8388608            //  + 131,072  fp32 [B][16][512] float2
#define WTF_OFF 8519680          //  + 786,432  fp32 [3][512 d][512 o]
#define ZP_OFF 9306112           //  +1,572,864 fp32 [4 dch][B*3][16][512] float2
#define G_OFF 10878976           //  + 131,072  fp32 [B][16][2][512]
#define V_OFF 11010048           //  +   8,192  fp32 [B][2][512]
#define STATS_OFF 11018240       //  +  65,536  fp32 [B*4096] float2 (mu, rstd)

// ---------------------------------------------------------------------------
// K0: transpose conv_w (O,I,3) -> wTf[t][d][o] (coalesced o-writes)
// ---------------------------------------------------------------------------
__global__ __launch_bounds__(256) void k_transpose_w(
    const float* __restrict__ cw, float* __restrict__ wTf) {
  int idx = blockIdx.x * 256 + threadIdx.x;  // 786432
  int o = idx & 511;
  int d = (idx >> 9) & 511;
  int t = idx >> 18;
  wTf[idx] = cw[o * 1536 + d * 3 + t];
}

// ---------------------------------------------------------------------------
// K1a: per-row LayerNorm stats. Grid 1024 x 256 thr; wave handles 8 rows.
// Memory-bound single pass over x (67 MB).
// ---------------------------------------------------------------------------
__global__ __launch_bounds__(256) void k_stats(const float* __restrict__ x,
                                               float2* __restrict__ stats) {
  int wave = threadIdx.x >> 6, lane = threadIdx.x & 63;
  int row0 = blockIdx.x * 32 + wave * 8;
  for (int j = 0; j < 8; ++j) {
    int row = row0 + j;
    const float4* px = (const float4*)(x + ((size_t)row << 9));
    float4 v0 = px[lane * 2];
    float4 v1 = px[lane * 2 + 1];
    float ps = v0.x + v0.y + v0.z + v0.w + v1.x + v1.y + v1.z + v1.w;
    float pq = v0.x * v0.x + v0.y * v0.y + v0.z * v0.z + v0.w * v0.w +
               v1.x * v1.x + v1.y * v1.y + v1.z * v1.z + v1.w * v1.w;
#pragma unroll
    for (int off = 32; off > 0; off >>= 1) {
      ps += __shfl_down(ps, off);
      pq += __shfl_down(pq, off);
    }
    if (lane == 0) {
      float mu = ps * (1.0f / Dn);
      float var = pq * (1.0f / Dn) - mu * mu;
      stats[row] = make_float2(mu, rsqrtf(var + 1e-5f));
    }
  }
}

// ---------------------------------------------------------------------------
// K1b: 16-mode DFT projection of LayerNorm output, per-64-row-chunk partials.
// Grid 1024 = b(8) x chunk(64) x dhalf(2); 1 d per thread (32 acc VGPRs).
// Depth-1 prefetch on the x column walk; stats/twiddles from LDS.
// ---------------------------------------------------------------------------
__global__ __launch_bounds__(256) void k_project(
    const float* __restrict__ x, const float* __restrict__ gamma,
    const float* __restrict__ beta, const float2* __restrict__ stats,
    float* __restrict__ partials) {
  int blk = blockIdx.x;
  int b = blk >> 7;
  int c = (blk >> 1) & 63;
  int dh = blk & 1;
  int tid = threadIdx.x;
  int s_base = c * 64;
  int d = dh * 256 + tid;

  __shared__ float2 s_tw[64 * MODES];  // 8 KB
  __shared__ float2 s_mv[64];
  if (tid < 64) s_mv[tid] = stats[(b << 12) + s_base + tid];
#pragma unroll
  for (int u = 0; u < 4; u++) {
    int e = tid * 4 + u;  // 1024
    int r = e >> 4, k = e & 15;
    int m = ((s_base + r) * k) & (Sn - 1);
    float sn, cn;
    __sincosf((float)m * ANGF, &sn, &cn);
    s_tw[e] = make_float2(cn, sn);
  }
  __syncthreads();

  float g = gamma[d], be = beta[d];
  float accRe[MODES], accIm[MODES];
#pragma unroll
  for (int k = 0; k < MODES; k++) { accRe[k] = 0.f; accIm[k] = 0.f; }

  const float* xp = x + (((size_t)(b * Sn + s_base)) << 9) + d;
  float xv_n = xp[0];
  for (int r = 0; r < 64; ++r) {
    float xv = xv_n;
    if (r < 63) xv_n = xp[(size_t)(r + 1) << 9];
    float2 mv = s_mv[r];
    float xn = (xv - mv.x) * mv.y * g + be;
    const float2* tw = &s_tw[r * MODES];
#pragma unroll
    for (int k = 0; k < MODES; k++) {
      float2 cs = tw[k];
      accRe[k] += xn * cs.x;
      accIm[k] -= xn * cs.y;
    }
  }
  size_t base = ((size_t)(b * 64 + c)) * MODES;
  float2* P = (float2*)partials;
#pragma unroll
  for (int k = 0; k < MODES; k++)
    P[(base + k) * Dn + d] = make_float2(accRe[k], accIm[k]);
}

// ---------------------------------------------------------------------------
// K2: reduce partials over 64 chunks, apply spectral weight, ortho norms
// (1/4096; 2/4096 for k>=1). Convention: xs = Re(E_k(s) * Yhat[k,d]).
// ---------------------------------------------------------------------------
__global__ __launch_bounds__(256) void k_reduce_modes(
    const float* __restrict__ partials, const float* __restrict__ wr,
    const float* __restrict__ wi, float* __restrict__ Y) {
  int idx = blockIdx.x * 256 + threadIdx.x;  // 65536
  int d = idx & 511;
  int k = (idx >> 9) & 15;
  int b = idx >> 13;
  const float2* P = (const float2*)partials;
  float re = 0.f, im = 0.f;
#pragma unroll 8
  for (int c = 0; c < 64; c++) {
    float2 p = P[(((size_t)(b * 64 + c)) * MODES + k) * Dn + d];
    re += p.x;
    im += p.y;
  }
  float wrv = wr[d * MODES + k];
  float wiv = wi[d * MODES + k];
  float yre = re * wrv - im * wiv;
  float yim = re * wiv + im * wrv;
  float scale = (k == 0) ? (1.0f / 4096.0f) : (2.0f / 4096.0f);
  ((float2*)Y)[((size_t)b * MODES + k) * Dn + d] =
      make_float2(yre * scale, yim * scale);
}

// ---------------------------------------------------------------------------
// KZ: Zp[dch][b,t][k][o] = sum_{d in chunk} Yhat[b,k,d] * w[o,d,t].
// Grid 768 = b(8) x t(3) x och(8) x dch(4). Wave = 4 modes, lanes = 64 o.
// ---------------------------------------------------------------------------
__global__ __launch_bounds__(256) void k_build_z(
    const float* __restrict__ Y, const float* __restrict__ wTf,
    float* __restrict__ Zp) {
  int blk = blockIdx.x;
  int b = blk / 96;
  int rem = blk % 96;
  int t = rem >> 5;
  int r2 = rem & 31;
  int och = r2 >> 2;
  int dch = r2 & 3;
  int tid = threadIdx.x;
  int oi = tid & 63, kq = tid >> 6;
  int o = och * 64 + oi;
  int d0 = dch * 128;

  __shared__ float2 Ys[MODES][128];  // 16 KB
  const float2* Y2 = (const float2*)Y;
#pragma unroll
  for (int i = 0; i < 8; i++) {
    int e = tid + i * 256;  // 2048
    int k = e >> 7, dd = e & 127;
    Ys[k][dd] = Y2[(((size_t)(b * MODES + k)) << 9) + d0 + dd];
  }
  __syncthreads();

  float zc[4] = {0.f, 0.f, 0.f, 0.f}, zs[4] = {0.f, 0.f, 0.f, 0.f};
  const float* wp = wTf + (((size_t)(t * Dn + d0)) << 9) + o;
  float wv_n = wp[0];
  for (int dd = 0; dd < 128; ++dd) {
    float wv = wv_n;
    if (dd < 127) wv_n = wp[(size_t)(dd + 1) << 9];
#pragma unroll
    for (int m = 0; m < 4; m++) {
      float2 y = Ys[kq * 4 + m][dd];
      zc[m] += y.x * wv;
      zs[m] += y.y * wv;
    }
  }
  float2* Z2 = (float2*)Zp;
#pragma unroll
  for (int m = 0; m < 4; m++) {
    int k = kq * 4 + m;
    Z2[(((size_t)(dch * 24 + b * 3 + t) * MODES + k)) << 9 | o] =
        make_float2(zc[m], zs[m]);
  }
}

// ---------------------------------------------------------------------------
// KG: G[b][k][o] = Yhat + e^{-i phi} Z0 + Z1 + e^{+i phi} Z2 (phi = 2pi k/S),
// summing the 4 d-chunk partials of Z; plus boundary vectors
// V0 = sum_k Re(e^{-i phi} Z0) (s=0 wrap), V1 = sum_k Re(Z2) (s=S-1).
// ---------------------------------------------------------------------------
__global__ __launch_bounds__(256) void k_build_g(
    const float* __restrict__ Y, const float* __restrict__ Zp,
    float* __restrict__ G, float* __restrict__ V) {
  int idx = blockIdx.x * 256 + threadIdx.x;
  const float2* Y2 = (const float2*)Y;
  const float2* Z2 = (const float2*)Zp;
  if (idx < 65536) {
    int o = idx & 511;
    int k = (idx >> 9) & 15;
    int b = idx >> 13;
    float2 z0 = make_float2(0.f, 0.f), z1 = z0, z2 = z0;
#pragma unroll
    for (int dch = 0; dch < 4; dch++) {
      float2 a0 = Z2[(((size_t)(dch * 24 + b * 3 + 0) * MODES + k)) << 9 | o];
      float2 a1 = Z2[(((size_t)(dch * 24 + b * 3 + 1) * MODES + k)) << 9 | o];
      float2 a2 = Z2[(((size_t)(dch * 24 + b * 3 + 2) * MODES + k)) << 9 | o];
      z0.x += a0.x; z0.y += a0.y;
      z1.x += a1.x; z1.y += a1.y;
      z2.x += a2.x; z2.y += a2.y;
    }
    float2 y = Y2[(((size_t)(b * MODES + k)) << 9) + o];
    float sf, cf;
    __sincosf((float)k * ANGF, &sf, &cf);
    float gc = y.x + (cf * z0.x + sf * z0.y) + z1.x + (cf * z2.x - sf * z2.y);
    float gs = y.y + (cf * z0.y - sf * z0.x) + z1.y + (cf * z2.y + sf * z2.x);
    G[(((size_t)(b * MODES + k) * 2 + 0)) << 9 | o] = gc;
    G[(((size_t)(b * MODES + k) * 2 + 1)) << 9 | o] = gs;
  } else if (idx < 65536 + 8192) {
    int j = idx - 65536;
    int o = j & 511;
    int comp = (j >> 9) & 1;
    int b = j >> 10;
    float v = 0.f;
#pragma unroll
    for (int k = 0; k < MODES; k++) {
      float2 z = make_float2(0.f, 0.f);
#pragma unroll
      for (int dch = 0; dch < 4; dch++) {
        float2 a = Z2[(((size_t)(dch * 24 + b * 3 + (comp ? 2 : 0)) * MODES +
                        k)) << 9 | o];
        z.x += a.x; z.y += a.y;
      }
      if (comp == 0) {
        float sf, cf;
        __sincosf((float)k * ANGF, &sf, &cf);
        v += cf * z.x + sf * z.y;
      } else {
        v += z.x;
      }
    }
    V[((size_t)(b * 2 + comp) << 9) + o] = v;
  }
}

// ---------------------------------------------------------------------------
// K5: out[b,s,o] = x + conv_b + sum_k (cos*Gc - sin*Gs), minus V0 at s=0 and
// V1 at s=4095. Grid 1024 = b(8) x 32-row tiles(128); 1 float2 of o per
// thread (G = 64 VGPRs), depth-1 prefetch on x.
// ---------------------------------------------------------------------------
__global__ __launch_bounds__(256) void k_apply(
    const float* __restrict__ x, const float* __restrict__ G,
    const float* __restrict__ V, const float* __restrict__ conv_b,
    float* __restrict__ out) {
  int b = blockIdx.x >> 7;
  int st = blockIdx.x & 127;
  int s0 = st * 32;
  int tid = threadIdx.x;
  int o0 = tid * 2;

  __shared__ float2 s_tw[32][MODES];  // 4 KB
#pragma unroll
  for (int u = 0; u < 2; u++) {
    int e = tid * 2 + u;  // 512
    int r = e >> 4, k = e & 15;
    int m = ((s0 + r) * k) & (Sn - 1);
    float sn, cn;
    __sincosf((float)m * ANGF, &sn, &cn);
    s_tw[r][k] = make_float2(cn, sn);
  }

  float2 Gc[MODES], Gs[MODES];
  const float2* Gp = (const float2*)(G + ((size_t)b * MODES * 2 * Dn));
#pragma unroll
  for (int k = 0; k < MODES; k++) {
    Gc[k] = Gp[(k * 2 + 0) * 256 + tid];
    Gs[k] = Gp[(k * 2 + 1) * 256 + tid];
  }
  float2 cb2 = *(const float2*)&conv_b[o0];
  __syncthreads();

  const float* xp = x + (((size_t)(b * Sn + s0)) << 9) + o0;
  float* op = out + (((size_t)(b * Sn + s0)) << 9) + o0;
  float2 xn_ = *(const float2*)xp;
  for (int rr = 0; rr < 32; ++rr) {
    float2 x2 = xn_;
    if (rr < 31) xn_ = *(const float2*)(xp + ((size_t)(rr + 1) << 9));
    float ax = 0.f, ay = 0.f;
    const float2* twr = s_tw[rr];
#pragma unroll
    for (int k = 0; k < MODES; k++) {
      float2 cs = twr[k];
      ax += cs.x * Gc[k].x - cs.y * Gs[k].x;
      ay += cs.x * Gc[k].y - cs.y * Gs[k].y;
    }
    int s = s0 + rr;
    if (s == 0) {
      float2 v = *(const float2*)&V[((size_t)(b * 2 + 0) << 9) + o0];
      ax -= v.x; ay -= v.y;
    }
    if (s == Sn - 1) {
      float2 v = *(const float2*)&V[((size_t)(b * 2 + 1) << 9) + o0];
      ax -= v.x; ay -= v.y;
    }
    float2 o2 = make_float2(x2.x + cb2.x + ax, x2.y + cb2.y + ay);
    *(float2*)(op + ((size_t)rr << 9)) = o2;
  }
}

// ---------------------------------------------------------------------------
extern "C" void kernel_launch(void* const* d_in, const int* in_sizes, int n_in,
                              void* d_out, int out_size, void* d_ws,
                              size_t ws_size, hipStream_t stream) {
  const float* x = (const float*)d_in[0];
  const float* gamma = (const float*)d_in[1];
  const float* beta = (const float*)d_in[2];
  const float* wr = (const float*)d_in[3];
  const float* wi = (const float*)d_in[4];
  const float* conv_w = (const float*)d_in[5];
  const float* conv_b = (const float*)d_in[6];
  float* out = (float*)d_out;

  float* ws = (float*)d_ws;
  float* partials = ws + PART_OFF;
  float* Y = ws + Y_OFF;
  float* wTf = ws + WTF_OFF;
  float* Zp = ws + ZP_OFF;
  float* G = ws + G_OFF;
  float* V = ws + V_OFF;
  float2* stats = (float2*)(ws + STATS_OFF);

  hipLaunchKernelGGL(k_transpose_w, dim3(3072), dim3(256), 0, stream, conv_w,
                     wTf);
  hipLaunchKernelGGL(k_stats, dim3(1024), dim3(256), 0, stream, x, stats);
  hipLaunchKernelGGL(k_project, dim3(1024), dim3(256), 0, stream, x, gamma,
                     beta, stats, partials);
  hipLaunchKernelGGL(k_reduce_modes, dim3(256), dim3(256), 0, stream, partials,
                     wr, wi, Y);
  hipLaunchKernelGGL(k_build_z, dim3(768), dim3(256), 0, stream, Y, wTf, Zp);
  hipLaunchKernelGGL(k_build_g, dim3(288), dim3(256), 0, stream, Y, Zp, G, V);
  hipLaunchKernelGGL(k_apply, dim3(1024), dim3(256), 0, stream, x, G, V,
                     conv_b, out);
}